// Round 5
// baseline (1805.131 us; speedup 1.0000x reference)
//
#include <hip/hip_runtime.h>

#define NN 20000
#define NE 320000
#define NG 64
#define D 128
#define D3 384
#define NRBF 20
#define NRBF_PAD 24      // ushorts per rbf row -> 48B, 16B-aligned
#define PI_F 3.14159265358979323846f
#define RCUT 10.0f

typedef unsigned int uint;
typedef unsigned short ushort;

__device__ __forceinline__ float silu_f(float x) {
    return x / (1.0f + __expf(-x));
}
// bf16 (stored as ushort) -> f32
__device__ __forceinline__ float b2f(ushort u) {
    return __uint_as_float(((uint)u) << 16);
}
// f32 -> bf16 RNE
__device__ __forceinline__ ushort f2b(float f) {
    uint u = __float_as_uint(f);
    u = u + 0x7fffu + ((u >> 16) & 1u);
    return (ushort)(u >> 16);
}
// packed-pair extract
__device__ __forceinline__ float plo(uint u) { return __uint_as_float(u << 16); }
__device__ __forceinline__ float phi_(uint u) { return __uint_as_float(u & 0xffff0000u); }

// ---------------------------------------------------------------- init
__global__ __launch_bounds__(256) void init_all(
    const int* __restrict__ atype, const float* __restrict__ emb,
    float* __restrict__ s, float* __restrict__ v, float* __restrict__ g,
    int* __restrict__ deg, uint* __restrict__ vh_u, int* __restrict__ bcount)
{
    int idx = blockIdx.x * blockDim.x + threadIdx.x;
    int stride = gridDim.x * blockDim.x;
    if (idx < NN * D) {
        int n = idx >> 7, d = idx & 127;
        s[idx] = emb[atype[n] * D + d];
    }
    if (idx < NG * D) g[idx] = 0.0f;
    if (idx < NN) deg[idx] = 0;
    if (idx < 64) bcount[idx] = 0;
    for (int i = idx; i < NN * 3 * D; i += stride) v[i] = 0.0f;
    for (int i = idx; i < NN * D3 / 2; i += stride) vh_u[i] = 0u;   // vh = bf16 zeros
}

// ---------------------------------------------------------------- CSR build (by dst)
__global__ __launch_bounds__(256) void csr_count(
    const int* __restrict__ dst, int* __restrict__ deg)
{
    int e = blockIdx.x * blockDim.x + threadIdx.x;
    if (e < NE) atomicAdd(&deg[dst[e]], 1);
}

__global__ __launch_bounds__(1024) void csr_scan(
    const int* __restrict__ deg, int* __restrict__ offs, int* __restrict__ cursor)
{
    __shared__ int part[1024];
    int t = threadIdx.x;
    const int per = (NN + 1023) / 1024;  // 20
    int base = t * per;
    int sum = 0;
    for (int i = 0; i < per; i++) {
        int idx = base + i;
        if (idx < NN) sum += deg[idx];
    }
    part[t] = sum;
    __syncthreads();
    for (int off = 1; off < 1024; off <<= 1) {
        int vv = (t >= off) ? part[t - off] : 0;
        __syncthreads();
        part[t] += vv;
        __syncthreads();
    }
    int run = part[t] - sum;  // exclusive base
    for (int i = 0; i < per; i++) {
        int idx = base + i;
        if (idx < NN) {
            offs[idx] = run;
            cursor[idx] = run;
            run += deg[idx];
        }
    }
    if (t == 1023) offs[NN] = run;  // == NE
}

__global__ __launch_bounds__(256) void csr_scatter(
    const int* __restrict__ dst, int* __restrict__ cursor, int* __restrict__ eid)
{
    int e = blockIdx.x * blockDim.x + threadIdx.x;
    if (e < NE) {
        int p = atomicAdd(&cursor[dst[e]], 1);
        eid[p] = e;
    }
}

// ---------------------------------------------------------------- degree sort (counting)
__global__ __launch_bounds__(256) void dbucket(
    const int* __restrict__ deg, int* __restrict__ bcount)
{
    int n = blockIdx.x * blockDim.x + threadIdx.x;
    if (n < NN) {
        int b = deg[n]; if (b > 63) b = 63;
        atomicAdd(&bcount[b], 1);
    }
}

__global__ void dscan(const int* __restrict__ bcount, int* __restrict__ bpos)
{
    if (threadIdx.x == 0) {
        int run = 0;
        for (int b = 63; b >= 0; b--) { bpos[b] = run; run += bcount[b]; }  // descending degree
    }
}

__global__ __launch_bounds__(256) void dscatter(
    const int* __restrict__ deg, int* __restrict__ bpos, int* __restrict__ perm)
{
    int n = blockIdx.x * blockDim.x + threadIdx.x;
    if (n < NN) {
        int b = deg[n]; if (b > 63) b = 63;
        int p = atomicAdd(&bpos[b], 1);
        perm[p] = n;
    }
}

// ---------------------------------------------------------------- edge geometry
// rbf_h[e][k] = bf16( sin((k+1)*pi*r/RCUT)/r * fcut ) ; geo[e] = {dir.xyz, fcut}
__global__ __launch_bounds__(256) void edge_geom(
    const float* __restrict__ evec,
    ushort* __restrict__ rbf_h, float4* __restrict__ geo)
{
    int e = blockIdx.x * blockDim.x + threadIdx.x;
    if (e >= NE) return;
    float x = evec[e * 3 + 0], y = evec[e * 3 + 1], z = evec[e * 3 + 2];
    float r = sqrtf(x * x + y * y + z * z);
    float inv = 1.0f / r;
    float f = (r < RCUT) ? 0.5f * (cosf(PI_F * r / RCUT) + 1.0f) : 0.0f;
    float4 g;
    g.x = x * inv; g.y = y * inv; g.z = z * inv; g.w = f;
    geo[e] = g;
    float base = PI_F * r / RCUT;
    float sf = inv * f;
    #pragma unroll
    for (int k = 0; k < NRBF; k++) {
        rbf_h[(size_t)e * NRBF_PAD + k] = f2b(sinf((float)(k + 1) * base) * sf);
    }
}

// ---------------------------------------------------------------- phi MLP (per node)
// phi = silu(s @ w1 + b1) @ w2 + b2, stored bf16 [n][seg*128 + j]
__global__ __launch_bounds__(256) void phi_mlp(
    const float* __restrict__ s,
    const float* __restrict__ w1, const float* __restrict__ b1,
    const float* __restrict__ w2, const float* __restrict__ b2,
    ushort* __restrict__ phi_h)
{
    __shared__ float sl[8][D];
    __shared__ float hl[8][D];
    int j = threadIdx.x & 127;
    int half = threadIdx.x >> 7;
    int n0 = blockIdx.x * 8;
    for (int t = threadIdx.x; t < 8 * D; t += 256)
        sl[t >> 7][t & 127] = s[n0 * D + t];
    __syncthreads();
    float acc[4];
    #pragma unroll
    for (int q = 0; q < 4; q++) acc[q] = b1[j];
    for (int k = 0; k < D; k++) {
        float w = w1[k * D + j];
        #pragma unroll
        for (int q = 0; q < 4; q++) acc[q] += sl[half * 4 + q][k] * w;
    }
    #pragma unroll
    for (int q = 0; q < 4; q++) hl[half * 4 + q][j] = silu_f(acc[q]);
    __syncthreads();
    float a0[4], a1[4], a2[4];
    #pragma unroll
    for (int q = 0; q < 4; q++) { a0[q] = b2[j]; a1[q] = b2[D + j]; a2[q] = b2[2 * D + j]; }
    for (int k = 0; k < D; k++) {
        float wa = w2[k * D3 + j];
        float wb = w2[k * D3 + D + j];
        float wc = w2[k * D3 + 2 * D + j];
        #pragma unroll
        for (int q = 0; q < 4; q++) {
            float h = hl[half * 4 + q][k];
            a0[q] += h * wa; a1[q] += h * wb; a2[q] += h * wc;
        }
    }
    #pragma unroll
    for (int q = 0; q < 4; q++) {
        int n = n0 + half * 4 + q;
        phi_h[(size_t)n * D3 + j]         = f2b(a0[q]);
        phi_h[(size_t)n * D3 + D + j]     = f2b(a1[q]);
        phi_h[(size_t)n * D3 + 2 * D + j] = f2b(a2[q]);
    }
}

// ---------------------------------------------------------------- node gather
// 512 threads = 8 waves = 4 nodes x 2 channel-halves; nodes via degree-sorted perm.
// Filter weights for this lane's channel live in 60 registers (edge-invariant);
// no LDS at all -> LDS pipe idle, occupancy capped only by VGPR (<=128).
__global__ __launch_bounds__(512, 4) void node_gather(
    const int* __restrict__ eid, const int* __restrict__ offs,
    const int* __restrict__ perm, const int* __restrict__ src,
    const ushort* __restrict__ phi_h,
    const float* __restrict__ s_old, const float* __restrict__ v_old,
    const ushort* __restrict__ vh,
    const ushort* __restrict__ rbf_h, const float4* __restrict__ geo,
    const float* __restrict__ filt_w, const float* __restrict__ filt_b,
    float* __restrict__ s_new, float* __restrict__ v_new)
{
    int wave = threadIdx.x >> 6;
    int lane = threadIdx.x & 63;
    int widx = blockIdx.x * 4 + (wave >> 1);
    if (widx >= NN) return;
    int node = perm[widx];
    int half = wave & 1;
    int d = half * 64 + lane;

    // edge-invariant per-channel filter column -> registers (L2-hot, coalesced)
    float wr0[NRBF], wr1[NRBF], wr2[NRBF];
    #pragma unroll
    for (int k = 0; k < NRBF; k++) {
        wr0[k] = filt_w[k * D3 + d];
        wr1[k] = filt_w[k * D3 + D + d];
        wr2[k] = filt_w[k * D3 + 2 * D + d];
    }
    float fb0 = filt_b[d], fb1 = filt_b[D + d], fb2 = filt_b[2 * D + d];
    int e0 = offs[node], e1 = offs[node + 1];

    float acc_s = 0.f, av0 = 0.f, av1 = 0.f, av2 = 0.f;

    for (int i = e0; i < e1; i += 2) {
        bool hb = (i + 1 < e1);
        int ea = eid[i], eb = eid[hb ? i + 1 : i];
        float mb = hb ? 1.0f : 0.0f;
        int sa = src[ea], sb = src[eb];
        float4 ga = geo[ea], gb = geo[eb];
        const uint4* rpa = (const uint4*)(rbf_h + (size_t)ea * NRBF_PAD);
        const uint4* rpb = (const uint4*)(rbf_h + (size_t)eb * NRBF_PAD);
        uint4 ra0 = rpa[0], ra1 = rpa[1];
        uint2 ra2 = *(const uint2*)(rpa + 2);
        uint4 rb0 = rpb[0], rb1 = rpb[1];
        uint2 rb2 = *(const uint2*)(rpb + 2);
        const ushort* ppa = phi_h + (size_t)sa * D3 + d;
        const ushort* ppb = phi_h + (size_t)sb * D3 + d;
        const ushort* qva = vh + (size_t)sa * D3 + d;
        const ushort* qvb = vh + (size_t)sb * D3 + d;
        float pa0 = b2f(ppa[0]), pa1 = b2f(ppa[D]), pa2 = b2f(ppa[2 * D]);
        float pb0 = b2f(ppb[0]), pb1 = b2f(ppb[D]), pb2 = b2f(ppb[2 * D]);
        float va0 = b2f(qva[0]), va1 = b2f(qva[D]), va2 = b2f(qva[2 * D]);
        float vb0 = b2f(qvb[0]), vb1 = b2f(qvb[D]), vb2 = b2f(qvb[2 * D]);

        float Wa0 = ga.w * fb0, Wa1 = ga.w * fb1, Wa2 = ga.w * fb2;
        float Wb0 = gb.w * fb0, Wb1 = gb.w * fb1, Wb2 = gb.w * fb2;
        #define RSTEP(k, RA, RB) { \
            float ra_ = RA, rb_ = RB; \
            Wa0 += ra_ * wr0[k]; Wa1 += ra_ * wr1[k]; Wa2 += ra_ * wr2[k]; \
            Wb0 += rb_ * wr0[k]; Wb1 += rb_ * wr1[k]; Wb2 += rb_ * wr2[k]; }
        RSTEP(0,  plo(ra0.x), plo(rb0.x))  RSTEP(1,  phi_(ra0.x), phi_(rb0.x))
        RSTEP(2,  plo(ra0.y), plo(rb0.y))  RSTEP(3,  phi_(ra0.y), phi_(rb0.y))
        RSTEP(4,  plo(ra0.z), plo(rb0.z))  RSTEP(5,  phi_(ra0.z), phi_(rb0.z))
        RSTEP(6,  plo(ra0.w), plo(rb0.w))  RSTEP(7,  phi_(ra0.w), phi_(rb0.w))
        RSTEP(8,  plo(ra1.x), plo(rb1.x))  RSTEP(9,  phi_(ra1.x), phi_(rb1.x))
        RSTEP(10, plo(ra1.y), plo(rb1.y))  RSTEP(11, phi_(ra1.y), phi_(rb1.y))
        RSTEP(12, plo(ra1.z), plo(rb1.z))  RSTEP(13, phi_(ra1.z), phi_(rb1.z))
        RSTEP(14, plo(ra1.w), plo(rb1.w))  RSTEP(15, phi_(ra1.w), phi_(rb1.w))
        RSTEP(16, plo(ra2.x), plo(rb2.x))  RSTEP(17, phi_(ra2.x), phi_(rb2.x))
        RSTEP(18, plo(ra2.y), plo(rb2.y))  RSTEP(19, phi_(ra2.y), phi_(rb2.y))
        #undef RSTEP

        float m1a = pa0 * Wa0, m2a = pa1 * Wa1, m3a = pa2 * Wa2;
        float m1b = pb0 * Wb0 * mb, m2b = pb1 * Wb1 * mb, m3b = pb2 * Wb2 * mb;
        acc_s += m2a + m2b;
        av0 += va0 * m1a + ga.x * m3a + vb0 * m1b + gb.x * m3b;
        av1 += va1 * m1a + ga.y * m3a + vb1 * m1b + gb.y * m3b;
        av2 += va2 * m1a + ga.z * m3a + vb2 * m1b + gb.z * m3b;
    }

    s_new[node * D + d] = s_old[node * D + d] + acc_s;
    v_new[(node * 3 + 0) * D + d] = v_old[(node * 3 + 0) * D + d] + av0;
    v_new[(node * 3 + 1) * D + d] = v_old[(node * 3 + 1) * D + d] + av1;
    v_new[(node * 3 + 2) * D + d] = v_old[(node * 3 + 2) * D + d] + av2;
}

// ---------------------------------------------------------------- U/Vp/UV/Vn (per node)
__global__ __launch_bounds__(256) void node_uv(
    const float* __restrict__ v,
    const float* __restrict__ Uw, const float* __restrict__ Vw,
    float* __restrict__ U, float* __restrict__ UV, float* __restrict__ Vn)
{
    __shared__ float vl[4][3][D];
    int j = threadIdx.x & 127;
    int half = threadIdx.x >> 7;
    int n0 = blockIdx.x * 4;
    for (int t = threadIdx.x; t < 4 * 3 * D; t += 256)
        vl[t / 384][(t / 128) % 3][t & 127] = v[n0 * 384 + t];
    __syncthreads();
    float u[2][3] = {{0,0,0},{0,0,0}};
    float p[2][3] = {{0,0,0},{0,0,0}};
    for (int k = 0; k < D; k++) {
        float wu = Uw[k * D + j], wv = Vw[k * D + j];
        #pragma unroll
        for (int q = 0; q < 2; q++)
            #pragma unroll
            for (int i = 0; i < 3; i++) {
                float vv = vl[half * 2 + q][i][k];
                u[q][i] += vv * wu;
                p[q][i] += vv * wv;
            }
    }
    #pragma unroll
    for (int q = 0; q < 2; q++) {
        int n = n0 + half * 2 + q;
        float uv = 0.0f, nn = 0.0f;
        #pragma unroll
        for (int i = 0; i < 3; i++) {
            uv += u[q][i] * p[q][i];
            nn += p[q][i] * p[q][i];
        }
        UV[n * D + j] = uv;
        Vn[n * D + j] = sqrtf(nn);
        #pragma unroll
        for (int i = 0; i < 3; i++) U[(n * 3 + i) * D + j] = u[q][i];
    }
}

// ---------------------------------------------------------------- update MLP + apply
// also writes bf16 shadow of the final v for next round's gather
__global__ __launch_bounds__(256) void node_update(
    float* __restrict__ s, float* __restrict__ v, ushort* __restrict__ vh,
    const float* __restrict__ Vn, const float* __restrict__ UV, const float* __restrict__ U,
    const float* __restrict__ w1, const float* __restrict__ b1,
    const float* __restrict__ w2, const float* __restrict__ b2)
{
    __shared__ float xl[8][2 * D];
    __shared__ float hl[8][D];
    int j = threadIdx.x & 127;
    int half = threadIdx.x >> 7;
    int n0 = blockIdx.x * 8;
    for (int t = threadIdx.x; t < 8 * 2 * D; t += 256) {
        int r = t >> 8, c = t & 255;
        int n = n0 + r;
        xl[r][c] = (c < D) ? Vn[n * D + c] : s[n * D + c - D];
    }
    __syncthreads();
    float acc[4];
    #pragma unroll
    for (int q = 0; q < 4; q++) acc[q] = b1[j];
    for (int k = 0; k < 2 * D; k++) {
        float w = w1[k * D + j];
        #pragma unroll
        for (int q = 0; q < 4; q++) acc[q] += xl[half * 4 + q][k] * w;
    }
    #pragma unroll
    for (int q = 0; q < 4; q++) hl[half * 4 + q][j] = silu_f(acc[q]);
    __syncthreads();
    float a0[4], a1[4], a2[4];
    #pragma unroll
    for (int q = 0; q < 4; q++) { a0[q] = b2[j]; a1[q] = b2[D + j]; a2[q] = b2[2 * D + j]; }
    for (int k = 0; k < D; k++) {
        float wa = w2[k * D3 + j];
        float wb = w2[k * D3 + D + j];
        float wc = w2[k * D3 + 2 * D + j];
        #pragma unroll
        for (int q = 0; q < 4; q++) {
            float h = hl[half * 4 + q][k];
            a0[q] += h * wa; a1[q] += h * wb; a2[q] += h * wc;
        }
    }
    #pragma unroll
    for (int q = 0; q < 4; q++) {
        int n = n0 + half * 4 + q;
        float sv  = xl[half * 4 + q][D + j];
        float avv = a0[q], asv = a1[q], ass = a2[q];
        s[n * D + j] = sv + ass + UV[n * D + j] * asv;
        #pragma unroll
        for (int i = 0; i < 3; i++) {
            int idx = (n * 3 + i) * D + j;
            float vf = v[idx] + U[idx] * avv;
            v[idx] = vf;
            vh[idx] = f2b(vf);
        }
    }
}

// ---------------------------------------------------------------- graph segment sum
__global__ __launch_bounds__(128) void graph_sum(
    const float* __restrict__ s, const int* __restrict__ gi, float* __restrict__ g)
{
    int d = threadIdx.x;
    int n0 = blockIdx.x * 64;
    int n1 = n0 + 64; if (n1 > NN) n1 = NN;
    if (n0 >= NN) return;
    int cur = gi[n0];
    float acc = 0.0f;
    for (int n = n0; n < n1; n++) {
        int gn = gi[n];
        if (gn != cur) { atomicAdd(&g[cur * D + d], acc); acc = 0.0f; cur = gn; }
        acc += s[n * D + d];
    }
    atomicAdd(&g[cur * D + d], acc);
}

// ---------------------------------------------------------------- readout
__global__ __launch_bounds__(128) void out_mlp(
    const float* __restrict__ g,
    const float* __restrict__ w1, const float* __restrict__ b1,
    const float* __restrict__ w2, const float* __restrict__ b2,
    float* __restrict__ out)
{
    __shared__ float gl[D];
    __shared__ float red[2];
    int j = threadIdx.x;
    int gr = blockIdx.x;
    gl[j] = g[gr * D + j];
    __syncthreads();
    float acc = b1[j];
    for (int k = 0; k < D; k++) acc += gl[k] * w1[k * D + j];
    float h = silu_f(acc) * w2[j];
    #pragma unroll
    for (int off = 32; off >= 1; off >>= 1) h += __shfl_down(h, off);
    if ((j & 63) == 0) red[j >> 6] = h;
    __syncthreads();
    if (j == 0) out[gr] = red[0] + red[1] + b2[0];
}

// ================================================================ launch
extern "C" void kernel_launch(void* const* d_in, const int* in_sizes, int n_in,
                              void* d_out, int out_size, void* d_ws, size_t ws_size,
                              hipStream_t stream)
{
    const int*   edge_src   = (const int*)  d_in[0];
    const int*   edge_dst   = (const int*)  d_in[1];
    const float* edge_vec   = (const float*)d_in[2];
    const int*   atom_types = (const int*)  d_in[3];
    const int*   node_gi    = (const int*)  d_in[4];
    const float* embedding  = (const float*)d_in[5];
    const float* phi_w1     = (const float*)d_in[6];
    const float* phi_b1     = (const float*)d_in[7];
    const float* phi_w2     = (const float*)d_in[8];
    const float* phi_b2     = (const float*)d_in[9];
    const float* filt_w     = (const float*)d_in[10];
    const float* filt_b     = (const float*)d_in[11];
    const float* upd_w1     = (const float*)d_in[12];
    const float* upd_b1     = (const float*)d_in[13];
    const float* upd_w2     = (const float*)d_in[14];
    const float* upd_b2     = (const float*)d_in[15];
    const float* U_w        = (const float*)d_in[16];
    const float* V_w        = (const float*)d_in[17];
    const float* out_w1     = (const float*)d_in[18];
    const float* out_b1     = (const float*)d_in[19];
    const float* out_w2     = (const float*)d_in[20];
    const float* out_b2     = (const float*)d_in[21];

    float* ws = (float*)d_ws;
    size_t o = 0;
    float* s_a   = ws + o; o += (size_t)NN * D;
    float* s_b   = ws + o; o += (size_t)NN * D;
    float* v_a   = ws + o; o += (size_t)NN * 3 * D;
    float* v_b   = ws + o; o += (size_t)NN * 3 * D;
    float* Ubuf  = ws + o; o += (size_t)NN * D3;      // U (fp32); phi_h (bf16) aliases its start
    float* UVb   = ws + o; o += (size_t)NN * D;
    float* Vnb   = ws + o; o += (size_t)NN * D;
    float* rbf_f = ws + o; o += (size_t)NE * NRBF_PAD / 2;   // bf16 storage
    float* geo   = ws + o; o += (size_t)NE * 4;
    float* vh_f  = ws + o; o += (size_t)NN * D3 / 2;          // bf16 storage
    float* g     = ws + o; o += (size_t)NG * D;
    int* deg     = (int*)(ws + o); o += NN;
    int* offs    = (int*)(ws + o); o += NN + 1;
    int* cursor  = (int*)(ws + o); o += NN;
    int* perm    = (int*)(ws + o); o += NN;
    int* bcount  = (int*)(ws + o); o += 64;
    int* bpos    = (int*)(ws + o); o += 64;
    int* eidb    = (int*)(ws + o); o += NE;

    ushort* phi_h = (ushort*)Ubuf;
    ushort* vh    = (ushort*)vh_f;
    ushort* rbf_h = (ushort*)rbf_f;

    init_all<<<NN * D / 256, 256, 0, stream>>>(atom_types, embedding, s_a, v_a, g,
                                               deg, (uint*)vh_f, bcount);
    csr_count<<<(NE + 255) / 256, 256, 0, stream>>>(edge_dst, deg);
    csr_scan<<<1, 1024, 0, stream>>>(deg, offs, cursor);
    csr_scatter<<<(NE + 255) / 256, 256, 0, stream>>>(edge_dst, cursor, eidb);
    dbucket<<<(NN + 255) / 256, 256, 0, stream>>>(deg, bcount);
    dscan<<<1, 64, 0, stream>>>(bcount, bpos);
    dscatter<<<(NN + 255) / 256, 256, 0, stream>>>(deg, bpos, perm);
    edge_geom<<<(NE + 255) / 256, 256, 0, stream>>>(edge_vec, rbf_h, (float4*)geo);

    float *s_cur = s_a, *v_cur = v_a, *s_nxt = s_b, *v_nxt = v_b;
    for (int round = 0; round < 2; round++) {
        phi_mlp<<<NN / 8, 256, 0, stream>>>(s_cur, phi_w1, phi_b1, phi_w2, phi_b2, phi_h);
        node_gather<<<NN / 4, 512, 0, stream>>>(eidb, offs, perm, edge_src, phi_h,
                                                s_cur, v_cur, vh, rbf_h,
                                                (const float4*)geo, filt_w, filt_b,
                                                s_nxt, v_nxt);
        node_uv<<<NN / 4, 256, 0, stream>>>(v_nxt, U_w, V_w, Ubuf, UVb, Vnb);
        node_update<<<NN / 8, 256, 0, stream>>>(s_nxt, v_nxt, vh, Vnb, UVb, Ubuf,
                                                upd_w1, upd_b1, upd_w2, upd_b2);
        float* ts = s_cur; s_cur = s_nxt; s_nxt = ts;
        float* tv = v_cur; v_cur = v_nxt; v_nxt = tv;
    }

    graph_sum<<<(NN + 63) / 64, 128, 0, stream>>>(s_cur, node_gi, g);
    out_mlp<<<NG, 128, 0, stream>>>(g, out_w1, out_b1, out_w2, out_b2, (float*)d_out);
}

// Round 6
// 973.939 us; speedup vs baseline: 1.8534x; 1.8534x over previous
//
#include <hip/hip_runtime.h>

#define NN 20000
#define NE 320000
#define NG 64
#define D 128
#define D3 384
#define NRBF 20
#define RBF_ROW 24       // fp32 per rbf row -> 96B, 16B-aligned
#define PI_F 3.14159265358979323846f
#define RCUT 10.0f

typedef unsigned int uint;
typedef unsigned short ushort;

__device__ __forceinline__ float silu_f(float x) {
    return x / (1.0f + __expf(-x));
}
// bf16 (stored as ushort) -> f32
__device__ __forceinline__ float b2f(ushort u) {
    return __uint_as_float(((uint)u) << 16);
}
// f32 -> bf16 RNE
__device__ __forceinline__ ushort f2b(float f) {
    uint u = __float_as_uint(f);
    u = u + 0x7fffu + ((u >> 16) & 1u);
    return (ushort)(u >> 16);
}

// ---------------------------------------------------------------- init
__global__ __launch_bounds__(256) void init_all(
    const int* __restrict__ atype, const float* __restrict__ emb,
    float* __restrict__ s, float* __restrict__ v, float* __restrict__ g,
    int* __restrict__ deg, uint* __restrict__ vh_u, int* __restrict__ bcount)
{
    int idx = blockIdx.x * blockDim.x + threadIdx.x;
    int stride = gridDim.x * blockDim.x;
    if (idx < NN * D) {
        int n = idx >> 7, d = idx & 127;
        s[idx] = emb[atype[n] * D + d];
    }
    if (idx < NG * D) g[idx] = 0.0f;
    if (idx < NN) deg[idx] = 0;
    if (idx < 64) bcount[idx] = 0;
    for (int i = idx; i < NN * 3 * D; i += stride) v[i] = 0.0f;
    for (int i = idx; i < NN * D3 / 2; i += stride) vh_u[i] = 0u;   // vh = bf16 zeros
}

// ---------------------------------------------------------------- CSR build (by dst)
__global__ __launch_bounds__(256) void csr_count(
    const int* __restrict__ dst, int* __restrict__ deg)
{
    int e = blockIdx.x * blockDim.x + threadIdx.x;
    if (e < NE) atomicAdd(&deg[dst[e]], 1);
}

__global__ __launch_bounds__(1024) void csr_scan(
    const int* __restrict__ deg, int* __restrict__ offs, int* __restrict__ cursor)
{
    __shared__ int part[1024];
    int t = threadIdx.x;
    const int per = (NN + 1023) / 1024;  // 20
    int base = t * per;
    int sum = 0;
    for (int i = 0; i < per; i++) {
        int idx = base + i;
        if (idx < NN) sum += deg[idx];
    }
    part[t] = sum;
    __syncthreads();
    for (int off = 1; off < 1024; off <<= 1) {
        int vv = (t >= off) ? part[t - off] : 0;
        __syncthreads();
        part[t] += vv;
        __syncthreads();
    }
    int run = part[t] - sum;  // exclusive base
    for (int i = 0; i < per; i++) {
        int idx = base + i;
        if (idx < NN) {
            offs[idx] = run;
            cursor[idx] = run;
            run += deg[idx];
        }
    }
    if (t == 1023) offs[NN] = run;  // == NE
}

__global__ __launch_bounds__(256) void csr_scatter(
    const int* __restrict__ dst, int* __restrict__ cursor, int* __restrict__ eid)
{
    int e = blockIdx.x * blockDim.x + threadIdx.x;
    if (e < NE) {
        int p = atomicAdd(&cursor[dst[e]], 1);
        eid[p] = e;
    }
}

// ---------------------------------------------------------------- degree sort (counting)
__global__ __launch_bounds__(256) void dbucket(
    const int* __restrict__ deg, int* __restrict__ bcount)
{
    int n = blockIdx.x * blockDim.x + threadIdx.x;
    if (n < NN) {
        int b = deg[n]; if (b > 63) b = 63;
        atomicAdd(&bcount[b], 1);
    }
}

__global__ void dscan(const int* __restrict__ bcount, int* __restrict__ bpos)
{
    if (threadIdx.x == 0) {
        int run = 0;
        for (int b = 63; b >= 0; b--) { bpos[b] = run; run += bcount[b]; }  // descending degree
    }
}

__global__ __launch_bounds__(256) void dscatter(
    const int* __restrict__ deg, int* __restrict__ bpos, int* __restrict__ perm)
{
    int n = blockIdx.x * blockDim.x + threadIdx.x;
    if (n < NN) {
        int b = deg[n]; if (b > 63) b = 63;
        int p = atomicAdd(&bpos[b], 1);
        perm[p] = n;
    }
}

// ---------------------------------------------------------------- edge geometry
// rbf[e][k] = sin((k+1)*pi*r/RCUT)/r * fcut (fp32, row padded to 24) ; geo[e]={dir,fcut}
__global__ __launch_bounds__(256) void edge_geom(
    const float* __restrict__ evec,
    float* __restrict__ rbf, float4* __restrict__ geo)
{
    int e = blockIdx.x * blockDim.x + threadIdx.x;
    if (e >= NE) return;
    float x = evec[e * 3 + 0], y = evec[e * 3 + 1], z = evec[e * 3 + 2];
    float r = sqrtf(x * x + y * y + z * z);
    float inv = 1.0f / r;
    float f = (r < RCUT) ? 0.5f * (cosf(PI_F * r / RCUT) + 1.0f) : 0.0f;
    float4 g;
    g.x = x * inv; g.y = y * inv; g.z = z * inv; g.w = f;
    geo[e] = g;
    float base = PI_F * r / RCUT;
    float sf = inv * f;
    #pragma unroll
    for (int k = 0; k < NRBF; k++) {
        rbf[(size_t)e * RBF_ROW + k] = sinf((float)(k + 1) * base) * sf;
    }
}

// ---------------------------------------------------------------- phi MLP (per node)
// phi = silu(s @ w1 + b1) @ w2 + b2, stored bf16 [n][seg*128 + j]
__global__ __launch_bounds__(256) void phi_mlp(
    const float* __restrict__ s,
    const float* __restrict__ w1, const float* __restrict__ b1,
    const float* __restrict__ w2, const float* __restrict__ b2,
    ushort* __restrict__ phi_h)
{
    __shared__ float sl[8][D];
    __shared__ float hl[8][D];
    int j = threadIdx.x & 127;
    int half = threadIdx.x >> 7;
    int n0 = blockIdx.x * 8;
    for (int t = threadIdx.x; t < 8 * D; t += 256)
        sl[t >> 7][t & 127] = s[n0 * D + t];
    __syncthreads();
    float acc[4];
    #pragma unroll
    for (int q = 0; q < 4; q++) acc[q] = b1[j];
    for (int k = 0; k < D; k++) {
        float w = w1[k * D + j];
        #pragma unroll
        for (int q = 0; q < 4; q++) acc[q] += sl[half * 4 + q][k] * w;
    }
    #pragma unroll
    for (int q = 0; q < 4; q++) hl[half * 4 + q][j] = silu_f(acc[q]);
    __syncthreads();
    float a0[4], a1[4], a2[4];
    #pragma unroll
    for (int q = 0; q < 4; q++) { a0[q] = b2[j]; a1[q] = b2[D + j]; a2[q] = b2[2 * D + j]; }
    for (int k = 0; k < D; k++) {
        float wa = w2[k * D3 + j];
        float wb = w2[k * D3 + D + j];
        float wc = w2[k * D3 + 2 * D + j];
        #pragma unroll
        for (int q = 0; q < 4; q++) {
            float h = hl[half * 4 + q][k];
            a0[q] += h * wa; a1[q] += h * wb; a2[q] += h * wc;
        }
    }
    #pragma unroll
    for (int q = 0; q < 4; q++) {
        int n = n0 + half * 4 + q;
        phi_h[(size_t)n * D3 + j]         = f2b(a0[q]);
        phi_h[(size_t)n * D3 + D + j]     = f2b(a1[q]);
        phi_h[(size_t)n * D3 + 2 * D + j] = f2b(a2[q]);
    }
}

// ---------------------------------------------------------------- node gather
// 512 threads = 8 waves = 4 nodes x 2 channel-halves; nodes via degree-sorted perm.
// Filter weights: 60 VGPRs/lane (edge-invariant). rbf: wave-uniform -> SGPR s_loads.
// waves_per_eu(4,4) pins occupancy so the allocator uses the full 128-VGPR budget
// instead of spilling to scratch (R4 failure mode).
__global__ __launch_bounds__(512)
__attribute__((amdgpu_waves_per_eu(4, 4)))
void node_gather(
    const int* __restrict__ eid, const int* __restrict__ offs,
    const int* __restrict__ perm, const int* __restrict__ src,
    const ushort* __restrict__ phi_h,
    const float* __restrict__ s_old, const float* __restrict__ v_old,
    const ushort* __restrict__ vh,
    const float* __restrict__ rbf, const float4* __restrict__ geo,
    const float* __restrict__ filt_w, const float* __restrict__ filt_b,
    float* __restrict__ s_new, float* __restrict__ v_new)
{
    int wave = threadIdx.x >> 6;
    int lane = threadIdx.x & 63;
    int widx = blockIdx.x * 4 + (wave >> 1);
    if (widx >= NN) return;
    int node = __builtin_amdgcn_readfirstlane(perm[widx]);
    int half = wave & 1;
    int d = half * 64 + lane;

    // edge-invariant per-channel filter column -> registers (L2-hot, coalesced)
    float wr0[NRBF], wr1[NRBF], wr2[NRBF];
    #pragma unroll
    for (int k = 0; k < NRBF; k++) {
        wr0[k] = filt_w[k * D3 + d];
        wr1[k] = filt_w[k * D3 + D + d];
        wr2[k] = filt_w[k * D3 + 2 * D + d];
    }
    float fb0 = filt_b[d], fb1 = filt_b[D + d], fb2 = filt_b[2 * D + d];
    int e0 = __builtin_amdgcn_readfirstlane(offs[node]);
    int e1 = __builtin_amdgcn_readfirstlane(offs[node + 1]);

    float acc_s = 0.f, av0 = 0.f, av1 = 0.f, av2 = 0.f;

    for (int i = e0; i < e1; i++) {
        int e  = __builtin_amdgcn_readfirstlane(eid[i]);
        int sn = __builtin_amdgcn_readfirstlane(src[e]);
        float4 g = geo[e];                                   // uniform
        const float*  rp = rbf + (size_t)e * RBF_ROW;        // uniform -> s_load
        const ushort* pp = phi_h + (size_t)sn * D3 + d;
        const ushort* qv = vh + (size_t)sn * D3 + d;
        float p0 = b2f(pp[0]), p1 = b2f(pp[D]), p2 = b2f(pp[2 * D]);
        float v0 = b2f(qv[0]), v1 = b2f(qv[D]), v2 = b2f(qv[2 * D]);

        float W0 = g.w * fb0, W1 = g.w * fb1, W2 = g.w * fb2;
        #pragma unroll
        for (int k = 0; k < NRBF; k++) {
            float rk = rp[k];                                // SGPR scalar
            W0 += rk * wr0[k];
            W1 += rk * wr1[k];
            W2 += rk * wr2[k];
        }
        float m1 = p0 * W0, m2 = p1 * W1, m3 = p2 * W2;
        acc_s += m2;
        av0 += v0 * m1 + g.x * m3;
        av1 += v1 * m1 + g.y * m3;
        av2 += v2 * m1 + g.z * m3;
    }

    s_new[node * D + d] = s_old[node * D + d] + acc_s;
    v_new[(node * 3 + 0) * D + d] = v_old[(node * 3 + 0) * D + d] + av0;
    v_new[(node * 3 + 1) * D + d] = v_old[(node * 3 + 1) * D + d] + av1;
    v_new[(node * 3 + 2) * D + d] = v_old[(node * 3 + 2) * D + d] + av2;
}

// ---------------------------------------------------------------- U/Vp/UV/Vn (per node)
__global__ __launch_bounds__(256) void node_uv(
    const float* __restrict__ v,
    const float* __restrict__ Uw, const float* __restrict__ Vw,
    float* __restrict__ U, float* __restrict__ UV, float* __restrict__ Vn)
{
    __shared__ float vl[4][3][D];
    int j = threadIdx.x & 127;
    int half = threadIdx.x >> 7;
    int n0 = blockIdx.x * 4;
    for (int t = threadIdx.x; t < 4 * 3 * D; t += 256)
        vl[t / 384][(t / 128) % 3][t & 127] = v[n0 * 384 + t];
    __syncthreads();
    float u[2][3] = {{0,0,0},{0,0,0}};
    float p[2][3] = {{0,0,0},{0,0,0}};
    for (int k = 0; k < D; k++) {
        float wu = Uw[k * D + j], wv = Vw[k * D + j];
        #pragma unroll
        for (int q = 0; q < 2; q++)
            #pragma unroll
            for (int i = 0; i < 3; i++) {
                float vv = vl[half * 2 + q][i][k];
                u[q][i] += vv * wu;
                p[q][i] += vv * wv;
            }
    }
    #pragma unroll
    for (int q = 0; q < 2; q++) {
        int n = n0 + half * 2 + q;
        float uv = 0.0f, nn = 0.0f;
        #pragma unroll
        for (int i = 0; i < 3; i++) {
            uv += u[q][i] * p[q][i];
            nn += p[q][i] * p[q][i];
        }
        UV[n * D + j] = uv;
        Vn[n * D + j] = sqrtf(nn);
        #pragma unroll
        for (int i = 0; i < 3; i++) U[(n * 3 + i) * D + j] = u[q][i];
    }
}

// ---------------------------------------------------------------- update MLP + apply
// also writes bf16 shadow of the final v for next round's gather
__global__ __launch_bounds__(256) void node_update(
    float* __restrict__ s, float* __restrict__ v, ushort* __restrict__ vh,
    const float* __restrict__ Vn, const float* __restrict__ UV, const float* __restrict__ U,
    const float* __restrict__ w1, const float* __restrict__ b1,
    const float* __restrict__ w2, const float* __restrict__ b2)
{
    __shared__ float xl[8][2 * D];
    __shared__ float hl[8][D];
    int j = threadIdx.x & 127;
    int half = threadIdx.x >> 7;
    int n0 = blockIdx.x * 8;
    for (int t = threadIdx.x; t < 8 * 2 * D; t += 256) {
        int r = t >> 8, c = t & 255;
        int n = n0 + r;
        xl[r][c] = (c < D) ? Vn[n * D + c] : s[n * D + c - D];
    }
    __syncthreads();
    float acc[4];
    #pragma unroll
    for (int q = 0; q < 4; q++) acc[q] = b1[j];
    for (int k = 0; k < 2 * D; k++) {
        float w = w1[k * D + j];
        #pragma unroll
        for (int q = 0; q < 4; q++) acc[q] += xl[half * 4 + q][k] * w;
    }
    #pragma unroll
    for (int q = 0; q < 4; q++) hl[half * 4 + q][j] = silu_f(acc[q]);
    __syncthreads();
    float a0[4], a1[4], a2[4];
    #pragma unroll
    for (int q = 0; q < 4; q++) { a0[q] = b2[j]; a1[q] = b2[D + j]; a2[q] = b2[2 * D + j]; }
    for (int k = 0; k < D; k++) {
        float wa = w2[k * D3 + j];
        float wb = w2[k * D3 + D + j];
        float wc = w2[k * D3 + 2 * D + j];
        #pragma unroll
        for (int q = 0; q < 4; q++) {
            float h = hl[half * 4 + q][k];
            a0[q] += h * wa; a1[q] += h * wb; a2[q] += h * wc;
        }
    }
    #pragma unroll
    for (int q = 0; q < 4; q++) {
        int n = n0 + half * 4 + q;
        float sv  = xl[half * 4 + q][D + j];
        float avv = a0[q], asv = a1[q], ass = a2[q];
        s[n * D + j] = sv + ass + UV[n * D + j] * asv;
        #pragma unroll
        for (int i = 0; i < 3; i++) {
            int idx = (n * 3 + i) * D + j;
            float vf = v[idx] + U[idx] * avv;
            v[idx] = vf;
            vh[idx] = f2b(vf);
        }
    }
}

// ---------------------------------------------------------------- graph segment sum
__global__ __launch_bounds__(128) void graph_sum(
    const float* __restrict__ s, const int* __restrict__ gi, float* __restrict__ g)
{
    int d = threadIdx.x;
    int n0 = blockIdx.x * 64;
    int n1 = n0 + 64; if (n1 > NN) n1 = NN;
    if (n0 >= NN) return;
    int cur = gi[n0];
    float acc = 0.0f;
    for (int n = n0; n < n1; n++) {
        int gn = gi[n];
        if (gn != cur) { atomicAdd(&g[cur * D + d], acc); acc = 0.0f; cur = gn; }
        acc += s[n * D + d];
    }
    atomicAdd(&g[cur * D + d], acc);
}

// ---------------------------------------------------------------- readout
__global__ __launch_bounds__(128) void out_mlp(
    const float* __restrict__ g,
    const float* __restrict__ w1, const float* __restrict__ b1,
    const float* __restrict__ w2, const float* __restrict__ b2,
    float* __restrict__ out)
{
    __shared__ float gl[D];
    __shared__ float red[2];
    int j = threadIdx.x;
    int gr = blockIdx.x;
    gl[j] = g[gr * D + j];
    __syncthreads();
    float acc = b1[j];
    for (int k = 0; k < D; k++) acc += gl[k] * w1[k * D + j];
    float h = silu_f(acc) * w2[j];
    #pragma unroll
    for (int off = 32; off >= 1; off >>= 1) h += __shfl_down(h, off);
    if ((j & 63) == 0) red[j >> 6] = h;
    __syncthreads();
    if (j == 0) out[gr] = red[0] + red[1] + b2[0];
}

// ================================================================ launch
extern "C" void kernel_launch(void* const* d_in, const int* in_sizes, int n_in,
                              void* d_out, int out_size, void* d_ws, size_t ws_size,
                              hipStream_t stream)
{
    const int*   edge_src   = (const int*)  d_in[0];
    const int*   edge_dst   = (const int*)  d_in[1];
    const float* edge_vec   = (const float*)d_in[2];
    const int*   atom_types = (const int*)  d_in[3];
    const int*   node_gi    = (const int*)  d_in[4];
    const float* embedding  = (const float*)d_in[5];
    const float* phi_w1     = (const float*)d_in[6];
    const float* phi_b1     = (const float*)d_in[7];
    const float* phi_w2     = (const float*)d_in[8];
    const float* phi_b2     = (const float*)d_in[9];
    const float* filt_w     = (const float*)d_in[10];
    const float* filt_b     = (const float*)d_in[11];
    const float* upd_w1     = (const float*)d_in[12];
    const float* upd_b1     = (const float*)d_in[13];
    const float* upd_w2     = (const float*)d_in[14];
    const float* upd_b2     = (const float*)d_in[15];
    const float* U_w        = (const float*)d_in[16];
    const float* V_w        = (const float*)d_in[17];
    const float* out_w1     = (const float*)d_in[18];
    const float* out_b1     = (const float*)d_in[19];
    const float* out_w2     = (const float*)d_in[20];
    const float* out_b2     = (const float*)d_in[21];

    float* ws = (float*)d_ws;
    size_t o = 0;
    float* s_a   = ws + o; o += (size_t)NN * D;
    float* s_b   = ws + o; o += (size_t)NN * D;
    float* v_a   = ws + o; o += (size_t)NN * 3 * D;
    float* v_b   = ws + o; o += (size_t)NN * 3 * D;
    float* Ubuf  = ws + o; o += (size_t)NN * D3;      // U (fp32); phi_h (bf16) aliases its start
    float* UVb   = ws + o; o += (size_t)NN * D;
    float* Vnb   = ws + o; o += (size_t)NN * D;
    float* rbf_f = ws + o; o += (size_t)NE * RBF_ROW;         // fp32, padded rows
    float* geo   = ws + o; o += (size_t)NE * 4;
    float* vh_f  = ws + o; o += (size_t)NN * D3 / 2;          // bf16 storage
    float* g     = ws + o; o += (size_t)NG * D;
    int* deg     = (int*)(ws + o); o += NN;
    int* offs    = (int*)(ws + o); o += NN + 1;
    int* cursor  = (int*)(ws + o); o += NN;
    int* perm    = (int*)(ws + o); o += NN;
    int* bcount  = (int*)(ws + o); o += 64;
    int* bpos    = (int*)(ws + o); o += 64;
    int* eidb    = (int*)(ws + o); o += NE;

    ushort* phi_h = (ushort*)Ubuf;
    ushort* vh    = (ushort*)vh_f;

    init_all<<<NN * D / 256, 256, 0, stream>>>(atom_types, embedding, s_a, v_a, g,
                                               deg, (uint*)vh_f, bcount);
    csr_count<<<(NE + 255) / 256, 256, 0, stream>>>(edge_dst, deg);
    csr_scan<<<1, 1024, 0, stream>>>(deg, offs, cursor);
    csr_scatter<<<(NE + 255) / 256, 256, 0, stream>>>(edge_dst, cursor, eidb);
    dbucket<<<(NN + 255) / 256, 256, 0, stream>>>(deg, bcount);
    dscan<<<1, 64, 0, stream>>>(bcount, bpos);
    dscatter<<<(NN + 255) / 256, 256, 0, stream>>>(deg, bpos, perm);
    edge_geom<<<(NE + 255) / 256, 256, 0, stream>>>(edge_vec, rbf_f, (float4*)geo);

    float *s_cur = s_a, *v_cur = v_a, *s_nxt = s_b, *v_nxt = v_b;
    for (int round = 0; round < 2; round++) {
        phi_mlp<<<NN / 8, 256, 0, stream>>>(s_cur, phi_w1, phi_b1, phi_w2, phi_b2, phi_h);
        node_gather<<<NN / 4, 512, 0, stream>>>(eidb, offs, perm, edge_src, phi_h,
                                                s_cur, v_cur, vh, rbf_f,
                                                (const float4*)geo, filt_w, filt_b,
                                                s_nxt, v_nxt);
        node_uv<<<NN / 4, 256, 0, stream>>>(v_nxt, U_w, V_w, Ubuf, UVb, Vnb);
        node_update<<<NN / 8, 256, 0, stream>>>(s_nxt, v_nxt, vh, Vnb, UVb, Ubuf,
                                                upd_w1, upd_b1, upd_w2, upd_b2);
        float* ts = s_cur; s_cur = s_nxt; s_nxt = ts;
        float* tv = v_cur; v_cur = v_nxt; v_nxt = tv;
    }

    graph_sum<<<(NN + 63) / 64, 128, 0, stream>>>(s_cur, node_gi, g);
    out_mlp<<<NG, 128, 0, stream>>>(g, out_w1, out_b1, out_w2, out_b2, (float*)d_out);
}